// Round 16
// baseline (1593.146 us; speedup 1.0000x reference)
//
#include <hip/hip_runtime.h>
#include <stdint.h>

// ---------- problem constants ----------
#define BATCH 1024
#define NVIEW 8
#define JN_   21
#define VTOK  168              // NVIEW*JN_
#define FDIM  512
#define NHEAD 4
#define DHEAD 128
#define MROWS (BATCH*VTOK)     // 172032
#define SCALE2 0.127517434f    // (1/sqrt(128)) * log2(e)

typedef __attribute__((ext_vector_type(8))) short s8v;
typedef __attribute__((ext_vector_type(4))) short s4v;
typedef __attribute__((ext_vector_type(4))) float f4v;

static __device__ __forceinline__ short f2bf(float f){
  unsigned u = __builtin_bit_cast(unsigned, f);
  unsigned r = (u + 0x7FFFu + ((u >> 16) & 1u)) >> 16;  // RNE
  return (short)(unsigned short)r;
}
static __device__ __forceinline__ float bf2f(short s){
  unsigned u = ((unsigned)(unsigned short)s) << 16;
  return __builtin_bit_cast(float, u);
}

#define GL16(gp, lp) __builtin_amdgcn_global_load_lds( \
    (__attribute__((address_space(1))) void*)(gp), \
    (__attribute__((address_space(3))) void*)(lp), 16, 0, 0)

// ---------- K0: fp32 -> bf16 weight conversion (wq|wk|wv|fcw|fc1|fc2) ----------
__global__ __launch_bounds__(256) void convert_w(
    const float* __restrict__ wq, const float* __restrict__ wk,
    const float* __restrict__ wv, const float* __restrict__ fcw,
    const float* __restrict__ fc1, const float* __restrict__ fc2,
    short* __restrict__ dst){
  int id = blockIdx.x * 256 + threadIdx.x;   // 393216 total
  int e = id * 4;
  int seg = e >> 18;            // 262144 elems per matrix
  int off = e & 262143;
  const float* s = seg==0?wq: seg==1?wk: seg==2?wv: seg==3?fcw: seg==4?fc1: fc2;
  float4 u = *(const float4*)(s + off);
  s4v o; o[0]=f2bf(u.x); o[1]=f2bf(u.y); o[2]=f2bf(u.z); o[3]=f2bf(u.w);
  *(s4v*)(dst + e) = o;
}

// ---------- K1: LN1 row kernel: h = LN(x) in bf16.  1 wave per row ----------
__global__ __launch_bounds__(256) void ln1_kernel(
    const float* __restrict__ x, const float* __restrict__ g,
    const float* __restrict__ bb, short* __restrict__ h){
  int row  = blockIdx.x * 4 + (threadIdx.x >> 6);
  int lane = threadIdx.x & 63;
  size_t base = (size_t)row * 512 + lane * 8;
  float4 u0 = *(const float4*)(x + base);
  float4 u1 = *(const float4*)(x + base + 4);
  float s = u0.x+u0.y+u0.z+u0.w + u1.x+u1.y+u1.z+u1.w;
  float q = u0.x*u0.x+u0.y*u0.y+u0.z*u0.z+u0.w*u0.w
          + u1.x*u1.x+u1.y*u1.y+u1.z*u1.z+u1.w*u1.w;
  #pragma unroll
  for (int o = 1; o < 64; o <<= 1){ s += __shfl_xor(s,o); q += __shfl_xor(q,o); }
  float mu = s * (1.f/512.f);
  float rstd = rsqrtf(q*(1.f/512.f) - mu*mu + 1e-6f);
  float4 g0 = *(const float4*)(g + lane*8),  g1 = *(const float4*)(g + lane*8 + 4);
  float4 b0 = *(const float4*)(bb + lane*8), b1 = *(const float4*)(bb + lane*8 + 4);
  s8v o_;
  o_[0]=f2bf((u0.x-mu)*rstd*g0.x+b0.x); o_[1]=f2bf((u0.y-mu)*rstd*g0.y+b0.y);
  o_[2]=f2bf((u0.z-mu)*rstd*g0.z+b0.z); o_[3]=f2bf((u0.w-mu)*rstd*g0.w+b0.w);
  o_[4]=f2bf((u1.x-mu)*rstd*g1.x+b1.x); o_[5]=f2bf((u1.y-mu)*rstd*g1.y+b1.y);
  o_[6]=f2bf((u1.z-mu)*rstd*g1.z+b1.z); o_[7]=f2bf((u1.w-mu)*rstd*g1.w+b1.w);
  *(s8v*)(h + base) = o_;
}

// ---------- K4b v2: g2 = LN2(x2b)  (x2b produced by MODE2 epilogue) ----------
__global__ __launch_bounds__(256) void ln2_kernel(
    const short* __restrict__ x2b, const float* __restrict__ g,
    const float* __restrict__ bb, short* __restrict__ g2){
  int row  = blockIdx.x * 4 + (threadIdx.x >> 6);
  int lane = threadIdx.x & 63;
  size_t base = (size_t)row * 512 + lane * 8;
  s8v xv = *(const s8v*)(x2b + base);
  float v[8];
  #pragma unroll
  for (int i = 0; i < 8; i++) v[i] = bf2f(xv[i]);
  float s = 0.f, q = 0.f;
  #pragma unroll
  for (int i = 0; i < 8; i++){ s += v[i]; q += v[i]*v[i]; }
  #pragma unroll
  for (int o = 1; o < 64; o <<= 1){ s += __shfl_xor(s,o); q += __shfl_xor(q,o); }
  float mu = s * (1.f/512.f);
  float rstd = rsqrtf(q*(1.f/512.f) - mu*mu + 1e-6f);
  float4 g0 = *(const float4*)(g + lane*8),  g1 = *(const float4*)(g + lane*8 + 4);
  float4 b0 = *(const float4*)(bb + lane*8), b1 = *(const float4*)(bb + lane*8 + 4);
  s8v o_;
  o_[0]=f2bf((v[0]-mu)*rstd*g0.x+b0.x); o_[1]=f2bf((v[1]-mu)*rstd*g0.y+b0.y);
  o_[2]=f2bf((v[2]-mu)*rstd*g0.z+b0.z); o_[3]=f2bf((v[3]-mu)*rstd*g0.w+b0.w);
  o_[4]=f2bf((v[4]-mu)*rstd*g1.x+b1.x); o_[5]=f2bf((v[5]-mu)*rstd*g1.y+b1.y);
  o_[6]=f2bf((v[6]-mu)*rstd*g1.z+b1.z); o_[7]=f2bf((v[7]-mu)*rstd*g1.w+b1.w);
  *(s8v*)(g2 + base) = o_;
}

// ---------- GEMM v16: PERSISTENT blocks, continuous K-tile stream ----------
// Grid = 256 (1 block/CU). Each block owns tiles it = bid + k*256 and runs
// them as ONE stream of K-tiles s: ring slots continue across tile
// boundaries (A slot (2s)%6, B slot (2s)%4); next tile's operands are
// staged during the current tile's last K-tiles; the group epilogue runs
// with those loads in flight. vmcnt never drains until the block's end.
// B-panel index (NTOF) is CONSTANT per block -> weight panel L2-hot.
// MODE 0: A=h, B=[wq|wk] -> q_ws/k_ws (+bq/bk)                 NT=2688
// MODE 1: A=wv, B=h      -> vt_ws coalesced-tok write (+bv)    NT=1344
// MODE 2: A=attn_out, B=fc_w -> x2b = bf16(x + . + fc_b)       NT=1344
// MODE 3: A=g2, B=fc1_w  -> a1 = relu(.) (+fc1_b)              NT=1344
// MODE 4: A=a1, B=fc2_w  -> d_out = . + fc2_b + x2b            NT=1344
template<int MODE>
__global__ __launch_bounds__(512, 1) void gemm_bt(
    const short* __restrict__ A, const short* __restrict__ Bm,
    const float* __restrict__ bias0, const float* __restrict__ bias1,
    const short* __restrict__ aux, const float* __restrict__ auxf,
    short* __restrict__ out0, short* __restrict__ out1,
    float* __restrict__ outf){
  __shared__ short lds[81920];           // 160 KB exactly
  short* const AL = lds;                 // 6 x 8192 shorts
  short* const BL = lds + 49152;         // 4 x 8192 shorts
  const int tid = threadIdx.x, lane = tid & 63;
  const int wid = tid >> 6, wr = wid >> 2, wc = wid & 3;   // 2M x 4N waves
  const int lg = lane >> 4, l15 = lane & 15, l7 = lane & 7;
  const int bid = blockIdx.x;            // 0..255
  constexpr int NT = (MODE == 0) ? 2688 : 1344;
  const int Send = ((NT - bid + 255) >> 8) << 3;   // my K-tile stream length

#define MTOF(it) ((MODE==0) ? ((it)>>2) : (MODE==1 ? ((it)&1) : ((it)>>1)))
#define NTOF(it) ((MODE==0) ? ((it)&3) : (MODE==1 ? ((it)>>1) : ((it)&1)))

  // stage BOTH halves of stream-K-tile s into slots (slot, slot+1): 4 GL16.
  // LDS dest linear; global chunk = (c&7)^(row&7) (inverse of read swizzle).
#define STAGEAS(s, slot) do {                                             \
    int it_ = bid + (((s) >> 3) << 8);                                    \
    const short* sb_ = A + (size_t)MTOF(it_)*131072 + (size_t)((s)&7)*64; \
    short* d_ = AL + (slot)*8192;                                         \
    _Pragma("unroll")                                                     \
    for (int h_ = 0; h_ < 2; h_++)                                        \
      _Pragma("unroll")                                                   \
      for (int r_ = 0; r_ < 2; r_++){                                     \
        int c_ = r_*512 + tid;                                            \
        int row_ = c_ >> 3, chk_ = (c_ & 7) ^ (row_ & 7);                 \
        GL16(sb_ + (size_t)h_*65536 + (size_t)row_*512 + chk_*8,          \
             d_ + h_*8192 + c_*8);                                        \
      } } while(0)
#define STAGEBS(s, slot) do {                                             \
    int it_ = bid + (((s) >> 3) << 8);                                    \
    const short* sb_ = Bm + (size_t)NTOF(it_)*131072 + (size_t)((s)&7)*64;\
    short* d_ = BL + (slot)*8192;                                         \
    _Pragma("unroll")                                                     \
    for (int h_ = 0; h_ < 2; h_++)                                        \
      _Pragma("unroll")                                                   \
      for (int r_ = 0; r_ < 2; r_++){                                     \
        int c_ = r_*512 + tid;                                            \
        int row_ = c_ >> 3, chk_ = (c_ & 7) ^ (row_ & 7);                 \
        GL16(sb_ + (size_t)h_*65536 + (size_t)row_*512 + chk_*8,          \
             d_ + h_*8192 + c_*8);                                        \
      } } while(0)

  // ---- prologue: stream tiles 0 (A+B) and 1 (A); wait oldest 8 ----
  STAGEAS(0, 0);
  STAGEBS(0, 0);
  STAGEAS(1, 2);
  asm volatile("s_waitcnt vmcnt(4)" ::: "memory");
  __builtin_amdgcn_s_barrier();

  f4v acc[8][4];
  #pragma unroll
  for (int m=0;m<8;m++)
    #pragma unroll
    for (int n=0;n<4;n++) acc[m][n] = f4v{0.f,0.f,0.f,0.f};

  int slotA = 0, slotB = 0;
  s8v a0[8], b0[4];
  for (int s = 0; s < Send; ++s){
    const short* Awp = AL + (slotA + wr)*8192 + l15*64;
    const short* Bwp = BL + (slotB + (wc>>1))*8192 + ((wc&1)*64 + l15)*64;
    const int c0 = (lg ^ l7) * 8;          // k-slice 0 swizzled chunk offset
    const int c1 = ((4 + lg) ^ l7) * 8;    // k-slice 1
    // ---- k-slice 0: reads; stage B(s+1); 32 MFMA ----
    #pragma unroll
    for (int n=0;n<4;n++) b0[n] = *(const s8v*)(Bwp + n*1024 + c0);
    #pragma unroll
    for (int m=0;m<8;m++) a0[m] = *(const s8v*)(Awp + m*1024 + c0);
    if (s + 1 < Send) STAGEBS(s+1, slotB ^ 2);
    __builtin_amdgcn_s_setprio(1);
    #pragma unroll
    for (int m=0;m<8;m++)
      #pragma unroll
      for (int n=0;n<4;n++)
        acc[m][n] = __builtin_amdgcn_mfma_f32_16x16x32_bf16(a0[m], b0[n], acc[m][n], 0,0,0);
    __builtin_amdgcn_s_setprio(0);
    // ---- k-slice 1: reads; stage A(s+2); 32 MFMA ----
    #pragma unroll
    for (int n=0;n<4;n++) b0[n] = *(const s8v*)(Bwp + n*1024 + c1);
    #pragma unroll
    for (int m=0;m<8;m++) a0[m] = *(const s8v*)(Awp + m*1024 + c1);
    if (s + 2 < Send) STAGEAS(s+2, (slotA >= 2) ? slotA - 2 : slotA + 4);
    __builtin_amdgcn_s_setprio(1);
    #pragma unroll
    for (int m=0;m<8;m++)
      #pragma unroll
      for (int n=0;n<4;n++)
        acc[m][n] = __builtin_amdgcn_mfma_f32_16x16x32_bf16(a0[m], b0[n], acc[m][n], 0,0,0);
    __builtin_amdgcn_s_setprio(0);
    // ---- K-tile boundary: counted vmcnt, single barrier ----
    if (s + 2 < Send)       asm volatile("s_waitcnt vmcnt(4)" ::: "memory");
    else if (s + 2 == Send) asm volatile("s_waitcnt vmcnt(0)" ::: "memory");
    __builtin_amdgcn_s_barrier();
    // ---- group end: epilogue for this output tile (loads stay in flight) ----
    if ((s & 7) == 7){
      const int it_ = bid + ((s >> 3) << 8);
      const size_t m0 = (size_t)MTOF(it_) * 256, n0 = (size_t)NTOF(it_) * 256;
      #pragma unroll
      for (int m=0;m<8;m++)
      #pragma unroll
      for (int n=0;n<4;n++)
      #pragma unroll
      for (int r=0;r<4;r++){
        int rowL = wr*128 + m*16 + lg*4 + r;
        int colL = wc*64 + n*16 + l15;
        size_t gm = m0 + rowL, gn = n0 + colL;
        float val = acc[m][n][r];
        if (MODE == 0){
          int nn = (int)gn;
          val += (nn < 512) ? bias0[nn] : bias1[nn - 512];
          int head = (nn >> 7) & 3, d = nn & 127;
          size_t b = gm / 168, tok = gm - b * 168;
          size_t idx = ((b*4 + head)*168 + tok)*128 + d;
          ((nn < 512) ? out0 : out1)[idx] = f2bf(val);
        } else if (MODE == 1){
          val += bias0[gm];
          int hh = ((int)gm >> 7) & 3, d = (int)gm & 127;
          size_t b = gn / 168, tok = gn - b * 168;
          out0[((b*4 + hh)*128 + d)*168 + tok] = f2bf(val);
        } else if (MODE == 2){
          val += bias0[gn] + auxf[gm*512 + gn];   // fused residual
          out0[gm*512 + gn] = f2bf(val);
        } else if (MODE == 3){
          val += bias0[gn];
          val = fmaxf(val, 0.f);
          out0[gm*512 + gn] = f2bf(val);
        } else {
          val += bias0[gn] + bf2f(aux[gm*512 + gn]);
          outf[gm*512 + gn] = val;
        }
      }
      #pragma unroll
      for (int m=0;m<8;m++)
        #pragma unroll
        for (int n=0;n<4;n++) acc[m][n] = f4v{0.f,0.f,0.f,0.f};
    }
    slotA = (slotA >= 4) ? 0 : slotA + 2;
    slotB ^= 2;
  }
#undef STAGEAS
#undef STAGEBS
#undef MTOF
#undef NTOF
}

// ---------- K3 v6: attention; K burst-staged to LDS, P overlays K,
// V-ring initial fills hoisted above softmax (hide cold-miss latency) ----------
// One block per (b,head), 4 waves x 48 rows. LDS 76.8 KB -> 2 blocks/CU.
__global__ __launch_bounds__(256, 2) void attn_kernel(
    const short* __restrict__ qg_, const short* __restrict__ kg_,
    const short* __restrict__ vtg_, const int* __restrict__ valid,
    short* __restrict__ outp){
  __shared__ short ldsb[38400];          // 76,800 B
  short* const Kl = ldsb;                // K: 2816 x 16B chunks (45,056 B)
  short* const Ps = ldsb;                // P overlays K after barrier

  int tid = threadIdx.x, lane = tid & 63, wid = tid >> 6;
  int lg = lane >> 4, l15 = lane & 15;
  int bh = blockIdx.x, b = bh >> 2, hh = bh & 3;
  const short* qg  = qg_  + (size_t)bh * (168*128);
  const short* kg  = kg_  + (size_t)bh * (168*128);
  const short* vtg = vtg_ + (size_t)bh * (128*168);

  // ---- burst-stage K: rows [176] x 128 cols; slot = chunk ^ ((row&1)<<2) ----
  #pragma unroll
  for (int r = 0; r < 11; r++){
    int c = r*256 + tid;
    int row = c >> 4;
    int g = (c & 15) ^ ((row & 1) << 2);
    GL16(kg + (size_t)row*128 + g*8, Kl + c*8);
  }

  int bits = 0;
  #pragma unroll
  for (int v = 0; v < 8; v++) bits |= (valid[b*8 + v] != 0) << v;
  if (bits == 0) bits = 255;
  float wk2[11];
  #pragma unroll
  for (int n = 0; n < 11; n++){
    int kt = n*16 + l15;
    int view = (kt * 781) >> 14;            // kt/21, exact for kt<176
    wk2[n] = ((bits >> view) & 1) ? 0.0f : -1.0e9f;
  }

  int row0 = wid * 48;
  f4v zf = {0.f,0.f,0.f,0.f};

  // ---- Q fragments from global (overlap with K staging) ----
  s8v qf[3][4];
  #pragma unroll
  for (int m=0;m<3;m++)
    #pragma unroll
    for (int kf=0;kf<4;kf++)
      qf[m][kf] = *(const s8v*)(qg + (size_t)(row0 + m*16 + l15)*128 + kf*32 + lg*8);

  asm volatile("s_waitcnt vmcnt(0)" ::: "memory");
  __builtin_amdgcn_s_barrier();

  // ---- S = Q @ K^T, K fragments from LDS ----
  f4v accS[3][11];
  #pragma unroll
  for (int m=0;m<3;m++)
    #pragma unroll
    for (int n=0;n<11;n++) accS[m][n] = zf;
  #pragma unroll
  for (int n=0;n<11;n++){
    s8v kb[4];
    #pragma unroll
    for (int kf=0;kf<4;kf++)
      kb[kf] = *(const s8v*)&Kl[(size_t)(n*16 + l15)*128 + (((kf*4 + lg) ^ ((l15 & 1) << 2)) << 3)];
    __builtin_amdgcn_s_setprio(1);
    #pragma unroll
    for (int kf=0;kf<4;kf++)
      #pragma unroll
      for (int m=0;m<3;m++)
        accS[m][n] = __builtin_amdgcn_mfma_f32_16x16x32_bf16(qf[m][kf], kb[kf], accS[m][n], 0,0,0);
    __builtin_amdgcn_s_setprio(0);
  }
  __builtin_amdgcn_s_barrier();   // all waves done reading K; P may overwrite

  // ---- V-ring fills 0,1 issued HERE: latency hides under softmax+P-write ----
  s8v vb[3][6];
  #pragma unroll
  for (int p=0;p<2;p++)
    #pragma unroll
    for (int kf=0;kf<6;kf++)
      vb[p][kf] = *(const s8v*)(vtg + (size_t)(p*16 + l15)*168 + kf*32 + lg*8);

  // ---- softmax (shift-free), write unnormalized P ----
  float inv_[3][4];
  #pragma unroll
  for (int m=0;m<3;m++){
    #pragma unroll
    for (int r=0;r<4;r++){
      int qtok = row0 + m*16 + lg*4 + r;
      float sum = 0.f;
      #pragma unroll
      for (int n=0;n<11;n++){
        float p = exp2f(fmaf(accS[m][n][r], SCALE2, wk2[n]));
        sum += p;
        Ps[qtok*200 + n*16 + l15] = f2bf(p);
      }
      sum += __shfl_xor(sum,1); sum += __shfl_xor(sum,2);
      sum += __shfl_xor(sum,4); sum += __shfl_xor(sum,8);
      inv_[m][r] = 1.0f / sum;
    }
  }
  {
    s8v z8 = {0,0,0,0,0,0,0,0};
    for (int i = lane; i < 96; i += 64){
      int rr = row0 + (i >> 1);
      *(s8v*)&Ps[rr*200 + 176 + (i&1)*8] = z8;
    }
  }

  // ---- O = P @ V with Vt 3-deep register prefetch ----
  s8v ap[3][6];
  #pragma unroll
  for (int m=0;m<3;m++)
    #pragma unroll
    for (int kf=0;kf<6;kf++)
      ap[m][kf] = *(const s8v*)&Ps[(row0 + m*16 + l15)*200 + kf*32 + lg*8];

  f4v accO[3][8];
  #pragma unroll
  for (int m=0;m<3;m++)
    #pragma unroll
    for (int n=0;n<8;n++) accO[m][n] = zf;
  #pragma unroll
  for (int n=0;n<8;n++){
    if (n < 6){
      #pragma unroll
      for (int kf=0;kf<6;kf++)
        vb[(n+2)%3][kf] = *(const s8v*)(vtg + (size_t)((n+2)*16 + l15)*168 + kf*32 + lg*8);
    }
    __builtin_amdgcn_s_setprio(1);
    #pragma unroll
    for (int kf=0;kf<6;kf++)
      #pragma unroll
      for (int m=0;m<3;m++)
        accO[m][n] = __builtin_amdgcn_mfma_f32_16x16x32_bf16(ap[m][kf], vb[n%3][kf], accO[m][n], 0,0,0);
    __builtin_amdgcn_s_setprio(0);
  }

  // ---- write attn_out [b*168+q][hh*128+d] bf16 (normalize) ----
  #pragma unroll
  for (int m=0;m<3;m++){
    #pragma unroll
    for (int r=0;r<4;r++){
      int qtok = row0 + m*16 + lg*4 + r;
      if (qtok < 168){
        float iv = inv_[m][r];
        size_t base = ((size_t)b*168 + qtok)*512 + hh*128;
        #pragma unroll
        for (int n=0;n<8;n++)
          outp[base + n*16 + l15] = f2bf(accO[m][n][r] * iv);
      }
    }
  }
}

// ---------- launch ----------
extern "C" void kernel_launch(void* const* d_in, const int* in_sizes, int n_in,
                              void* d_out, int out_size, void* d_ws, size_t ws_size,
                              hipStream_t stream) {
  const float* x     = (const float*)d_in[0];
  const int*   valid = (const int*)  d_in[1];
  const float* wq    = (const float*)d_in[2];
  const float* bq    = (const float*)d_in[3];
  const float* wk    = (const float*)d_in[4];
  const float* bk    = (const float*)d_in[5];
  const float* wv    = (const float*)d_in[6];
  const float* bv    = (const float*)d_in[7];
  const float* fcw   = (const float*)d_in[8];
  const float* fcb   = (const float*)d_in[9];
  const float* ln1g  = (const float*)d_in[10];
  const float* ln1b  = (const float*)d_in[11];
  const float* ln2g  = (const float*)d_in[12];
  const float* ln2b  = (const float*)d_in[13];
  const float* fc1w  = (const float*)d_in[14];
  const float* fc1b  = (const float*)d_in[15];
  const float* fc2w  = (const float*)d_in[16];
  const float* fc2b  = (const float*)d_in[17];

  char* ws = (char*)d_ws;
  short* h       = (short*)(ws + 0LL);            // later: attn_out, then g2
  short* q_ws    = (short*)(ws + 176160768LL);
  short* k_ws    = (short*)(ws + 352321536LL);    // later: a1
  short* vt_ws   = (short*)(ws + 528482304LL);    // later: x2b
  short* wb      = (short*)(ws + 704643072LL);    // bf16 weights [wq|wk|wv|fcw|fc1|fc2]
  short* attn_o  = h;
  short* g2      = h;
  short* a1      = k_ws;
  short* x2b     = vt_ws;
  float* outp    = (float*)d_out;

  convert_w<<<1536, 256, 0, stream>>>(wq, wk, wv, fcw, fc1w, fc2w, wb);
  ln1_kernel<<<MROWS/4, 256, 0, stream>>>(x, ln1g, ln1b, h);
  // QK projection (NT=2688 tiles, persistent grid 256)
  gemm_bt<0><<<256, 512, 0, stream>>>(h, wb, bq, bk, nullptr, nullptr, q_ws, k_ws, nullptr);
  // V^T projection (NT=1344)
  gemm_bt<1><<<256, 512, 0, stream>>>(wb + 524288, h, bv, nullptr, nullptr, nullptr, vt_ws, nullptr, nullptr);
  attn_kernel<<<BATCH*NHEAD, 256, 0, stream>>>(q_ws, k_ws, vt_ws, valid, attn_o);
  // output projection + fused residual: x2b = bf16(x + proj + fc_b)
  gemm_bt<2><<<256, 512, 0, stream>>>(attn_o, wb + 786432, fcb, nullptr, nullptr, x, x2b, nullptr, nullptr);
  ln2_kernel<<<MROWS/4, 256, 0, stream>>>(x2b, ln2g, ln2b, g2);
  // MLP
  gemm_bt<3><<<256, 512, 0, stream>>>(g2, wb + 1048576, fc1b, nullptr, nullptr, nullptr, a1, nullptr, nullptr);
  gemm_bt<4><<<256, 512, 0, stream>>>(a1, wb + 1310720, fc2b, nullptr, x2b, nullptr, nullptr, nullptr, outp);
}

// Round 17
// 1224.839 us; speedup vs baseline: 1.3007x; 1.3007x over previous
//
#include <hip/hip_runtime.h>
#include <stdint.h>

// ---------- problem constants ----------
#define BATCH 1024
#define NVIEW 8
#define JN_   21
#define VTOK  168              // NVIEW*JN_
#define FDIM  512
#define NHEAD 4
#define DHEAD 128
#define MROWS (BATCH*VTOK)     // 172032
#define SCALE2 0.127517434f    // (1/sqrt(128)) * log2(e)

typedef __attribute__((ext_vector_type(8))) short s8v;
typedef __attribute__((ext_vector_type(4))) short s4v;
typedef __attribute__((ext_vector_type(4))) float f4v;

static __device__ __forceinline__ short f2bf(float f){
  unsigned u = __builtin_bit_cast(unsigned, f);
  unsigned r = (u + 0x7FFFu + ((u >> 16) & 1u)) >> 16;  // RNE
  return (short)(unsigned short)r;
}
static __device__ __forceinline__ float bf2f(short s){
  unsigned u = ((unsigned)(unsigned short)s) << 16;
  return __builtin_bit_cast(float, u);
}

#define GL16(gp, lp) __builtin_amdgcn_global_load_lds( \
    (__attribute__((address_space(1))) void*)(gp), \
    (__attribute__((address_space(3))) void*)(lp), 16, 0, 0)

// ---------- K0: fp32 -> bf16 weight conversion (wq|wk|wv|fcw|fc1|fc2) ----------
__global__ __launch_bounds__(256) void convert_w(
    const float* __restrict__ wq, const float* __restrict__ wk,
    const float* __restrict__ wv, const float* __restrict__ fcw,
    const float* __restrict__ fc1, const float* __restrict__ fc2,
    short* __restrict__ dst){
  int id = blockIdx.x * 256 + threadIdx.x;   // 393216 total
  int e = id * 4;
  int seg = e >> 18;            // 262144 elems per matrix
  int off = e & 262143;
  const float* s = seg==0?wq: seg==1?wk: seg==2?wv: seg==3?fcw: seg==4?fc1: fc2;
  float4 u = *(const float4*)(s + off);
  s4v o; o[0]=f2bf(u.x); o[1]=f2bf(u.y); o[2]=f2bf(u.z); o[3]=f2bf(u.w);
  *(s4v*)(dst + e) = o;
}

// ---------- K1: LN1 row kernel: h = LN(x) in bf16.  1 wave per row ----------
__global__ __launch_bounds__(256) void ln1_kernel(
    const float* __restrict__ x, const float* __restrict__ g,
    const float* __restrict__ bb, short* __restrict__ h){
  int row  = blockIdx.x * 4 + (threadIdx.x >> 6);
  int lane = threadIdx.x & 63;
  size_t base = (size_t)row * 512 + lane * 8;
  float4 u0 = *(const float4*)(x + base);
  float4 u1 = *(const float4*)(x + base + 4);
  float s = u0.x+u0.y+u0.z+u0.w + u1.x+u1.y+u1.z+u1.w;
  float q = u0.x*u0.x+u0.y*u0.y+u0.z*u0.z+u0.w*u0.w
          + u1.x*u1.x+u1.y*u1.y+u1.z*u1.z+u1.w*u1.w;
  #pragma unroll
  for (int o = 1; o < 64; o <<= 1){ s += __shfl_xor(s,o); q += __shfl_xor(q,o); }
  float mu = s * (1.f/512.f);
  float rstd = rsqrtf(q*(1.f/512.f) - mu*mu + 1e-6f);
  float4 g0 = *(const float4*)(g + lane*8),  g1 = *(const float4*)(g + lane*8 + 4);
  float4 b0 = *(const float4*)(bb + lane*8), b1 = *(const float4*)(bb + lane*8 + 4);
  s8v o_;
  o_[0]=f2bf((u0.x-mu)*rstd*g0.x+b0.x); o_[1]=f2bf((u0.y-mu)*rstd*g0.y+b0.y);
  o_[2]=f2bf((u0.z-mu)*rstd*g0.z+b0.z); o_[3]=f2bf((u0.w-mu)*rstd*g0.w+b0.w);
  o_[4]=f2bf((u1.x-mu)*rstd*g1.x+b1.x); o_[5]=f2bf((u1.y-mu)*rstd*g1.y+b1.y);
  o_[6]=f2bf((u1.z-mu)*rstd*g1.z+b1.z); o_[7]=f2bf((u1.w-mu)*rstd*g1.w+b1.w);
  *(s8v*)(h + base) = o_;
}

// ---------- K4b v2: g2 = LN2(x2b)  (x2b produced by MODE2 epilogue) ----------
__global__ __launch_bounds__(256) void ln2_kernel(
    const short* __restrict__ x2b, const float* __restrict__ g,
    const float* __restrict__ bb, short* __restrict__ g2){
  int row  = blockIdx.x * 4 + (threadIdx.x >> 6);
  int lane = threadIdx.x & 63;
  size_t base = (size_t)row * 512 + lane * 8;
  s8v xv = *(const s8v*)(x2b + base);
  float v[8];
  #pragma unroll
  for (int i = 0; i < 8; i++) v[i] = bf2f(xv[i]);
  float s = 0.f, q = 0.f;
  #pragma unroll
  for (int i = 0; i < 8; i++){ s += v[i]; q += v[i]*v[i]; }
  #pragma unroll
  for (int o = 1; o < 64; o <<= 1){ s += __shfl_xor(s,o); q += __shfl_xor(q,o); }
  float mu = s * (1.f/512.f);
  float rstd = rsqrtf(q*(1.f/512.f) - mu*mu + 1e-6f);
  float4 g0 = *(const float4*)(g + lane*8),  g1 = *(const float4*)(g + lane*8 + 4);
  float4 b0 = *(const float4*)(bb + lane*8), b1 = *(const float4*)(bb + lane*8 + 4);
  s8v o_;
  o_[0]=f2bf((v[0]-mu)*rstd*g0.x+b0.x); o_[1]=f2bf((v[1]-mu)*rstd*g0.y+b0.y);
  o_[2]=f2bf((v[2]-mu)*rstd*g0.z+b0.z); o_[3]=f2bf((v[3]-mu)*rstd*g0.w+b0.w);
  o_[4]=f2bf((v[4]-mu)*rstd*g1.x+b1.x); o_[5]=f2bf((v[5]-mu)*rstd*g1.y+b1.y);
  o_[6]=f2bf((v[6]-mu)*rstd*g1.z+b1.z); o_[7]=f2bf((v[7]-mu)*rstd*g1.w+b1.w);
  *(s8v*)(g2 + base) = o_;
}

// ---------- GEMM v15 (= v11 schedule + fused MODE2 epilogue; QKV split) ----------
// 256x256 tile, BK=64, 8 waves (2M x 4N), per-wave 128x64 (8m x 4n 16x16).
// A-ring 6 halves (3 tiles), B-ring 4 halves (2 tiles), 160 KB.
// One boundary per K-tile: counted vmcnt(4) + single s_barrier (v11-best).
// MODE 0: A=h, B=[wq|wk] -> q_ws/k_ws (+bq/bk)
// MODE 1: A=wv, B=h      -> vt_ws [B,NH,128,V] coalesced-tok write (+bv)
// MODE 2: A=attn_out, B=fc_w -> x2b = bf16(x + . + fc_b)   [residual fused]
// MODE 3: A=g2, B=fc1_w  -> a1 = relu(.) bf16 (+fc1_b)
// MODE 4: A=a1, B=fc2_w  -> d_out f32 = . + fc2_b + x2b
template<int MODE>
__global__ __launch_bounds__(512, 1) void gemm_bt(
    const short* __restrict__ A, const short* __restrict__ Bm,
    const float* __restrict__ bias0, const float* __restrict__ bias1,
    const short* __restrict__ aux, const float* __restrict__ auxf,
    short* __restrict__ out0, short* __restrict__ out1,
    float* __restrict__ outf){
  __shared__ short lds[81920];           // 160 KB exactly
  short* const AL = lds;                 // 6 x 8192 shorts
  short* const BL = lds + 49152;         // 4 x 8192 shorts
  const int tid = threadIdx.x, lane = tid & 63;
  const int wid = tid >> 6, wr = wid >> 2, wc = wid & 3;   // 2M x 4N waves
  const int lg = lane >> 4, l15 = lane & 15, l7 = lane & 7;
  // T1: XCD-aware bijective swizzle (nwg % 8 == 0 for all launches here)
  const int nwg  = gridDim.x * gridDim.y;
  const int flat = blockIdx.y * gridDim.x + blockIdx.x;
  const int swz  = (flat & 7) * (nwg >> 3) + (flat >> 3);
  size_t mt, nt;
  if (MODE == 1){ mt = swz & 1; nt = (size_t)(swz >> 1); }
  else {
    constexpr int GX = (MODE == 0) ? 4 : 2;
    nt = swz % GX; mt = swz / GX;
  }
  const size_t m0 = mt * 256, n0 = nt * 256;
  const short* Ab = A + m0 * 512;
  const short* Bb = Bm + n0 * 512;

#define STAGEA(slot, tile, half) do {                                   \
    const short* s_ = Ab + (size_t)(half)*65536 + (tile)*64;            \
    short* d_ = AL + (slot)*8192;                                       \
    _Pragma("unroll")                                                   \
    for (int r_ = 0; r_ < 2; r_++){                                     \
      int c_ = r_*512 + tid;                                            \
      int row_ = c_ >> 3, chk_ = (c_ & 7) ^ (row_ & 7);                 \
      GL16(s_ + (size_t)row_*512 + chk_*8, d_ + c_*8);                  \
    } } while(0)
#define STAGEB(slot, tile, half) do {                                   \
    const short* s_ = Bb + (size_t)(half)*65536 + (tile)*64;            \
    short* d_ = BL + (slot)*8192;                                       \
    _Pragma("unroll")                                                   \
    for (int r_ = 0; r_ < 2; r_++){                                     \
      int c_ = r_*512 + tid;                                            \
      int row_ = c_ >> 3, chk_ = (c_ & 7) ^ (row_ & 7);                 \
      GL16(s_ + (size_t)row_*512 + chk_*8, d_ + c_*8);                  \
    } } while(0)

  // ---- prologue: A(0), B(0), A(1); wait the oldest 8 loads (A0,B0) ----
  STAGEA(0, 0, 0); STAGEA(1, 0, 1);
  STAGEB(0, 0, 0); STAGEB(1, 0, 1);
  STAGEA(2, 1, 0); STAGEA(3, 1, 1);
  asm volatile("s_waitcnt vmcnt(4)" ::: "memory");
  __builtin_amdgcn_s_barrier();

  f4v acc[8][4];
  #pragma unroll
  for (int m=0;m<8;m++)
    #pragma unroll
    for (int n=0;n<4;n++) acc[m][n] = f4v{0.f,0.f,0.f,0.f};

  s8v a0[8], b0[4];
  #pragma unroll
  for (int t = 0; t < 8; ++t){
    const short* Awp = AL + ((2*t)%6 + wr)*8192 + l15*64;
    const short* Bwp = BL + ((2*t)%4 + (wc>>1))*8192 + ((wc&1)*64 + l15)*64;
    const int c0 = (lg ^ l7) * 8;          // k-slice 0 swizzled chunk offset
    const int c1 = ((4 + lg) ^ l7) * 8;    // k-slice 1
    // ---- k-slice 0: reads; stage B(t+1); 32 MFMA ----
    #pragma unroll
    for (int n=0;n<4;n++) b0[n] = *(const s8v*)(Bwp + n*1024 + c0);
    #pragma unroll
    for (int m=0;m<8;m++) a0[m] = *(const s8v*)(Awp + m*1024 + c0);
    if (t < 7){ STAGEB((2*t+2)%4, t+1, 0); STAGEB((2*t+2)%4 + 1, t+1, 1); }
    __builtin_amdgcn_s_setprio(1);
    #pragma unroll
    for (int m=0;m<8;m++)
      #pragma unroll
      for (int n=0;n<4;n++)
        acc[m][n] = __builtin_amdgcn_mfma_f32_16x16x32_bf16(a0[m], b0[n], acc[m][n], 0,0,0);
    __builtin_amdgcn_s_setprio(0);
    // ---- k-slice 1: reads; stage A(t+2); 32 MFMA ----
    #pragma unroll
    for (int n=0;n<4;n++) b0[n] = *(const s8v*)(Bwp + n*1024 + c1);
    #pragma unroll
    for (int m=0;m<8;m++) a0[m] = *(const s8v*)(Awp + m*1024 + c1);
    if (t < 6){ STAGEA((2*t+4)%6, t+2, 0); STAGEA((2*t+4)%6 + 1, t+2, 1); }
    __builtin_amdgcn_s_setprio(1);
    #pragma unroll
    for (int m=0;m<8;m++)
      #pragma unroll
      for (int n=0;n<4;n++)
        acc[m][n] = __builtin_amdgcn_mfma_f32_16x16x32_bf16(a0[m], b0[n], acc[m][n], 0,0,0);
    __builtin_amdgcn_s_setprio(0);
    // ---- K-tile boundary: counted vmcnt, single barrier ----
    if (t < 6)       asm volatile("s_waitcnt vmcnt(4)" ::: "memory");
    else if (t == 6) asm volatile("s_waitcnt vmcnt(0)" ::: "memory");
    __builtin_amdgcn_s_barrier();
  }
#undef STAGEA
#undef STAGEB

  // ---- epilogue (16x16 C/D layout: col=l15, row=lg*4+r) ----
  #pragma unroll
  for (int m=0;m<8;m++)
  #pragma unroll
  for (int n=0;n<4;n++)
  #pragma unroll
  for (int r=0;r<4;r++){
    int rowL = wr*128 + m*16 + lg*4 + r;
    int colL = wc*64 + n*16 + l15;
    size_t gm = m0 + rowL, gn = n0 + colL;
    float val = acc[m][n][r];
    if (MODE == 0){
      int nn = (int)gn;
      val += (nn < 512) ? bias0[nn] : bias1[nn - 512];
      int head = (nn >> 7) & 3, d = nn & 127;
      size_t b = gm / 168, tok = gm - b * 168;
      size_t idx = ((b*4 + head)*168 + tok)*128 + d;
      ((nn < 512) ? out0 : out1)[idx] = f2bf(val);
    } else if (MODE == 1){
      val += bias0[gm];
      int hh = ((int)gm >> 7) & 3, d = (int)gm & 127;
      size_t b = gn / 168, tok = gn - b * 168;
      out0[((b*4 + hh)*128 + d)*168 + tok] = f2bf(val);
    } else if (MODE == 2){
      // fused residual: x2b = bf16(x + proj + fc_b)
      val += bias0[gn] + auxf[gm*512 + gn];
      out0[gm*512 + gn] = f2bf(val);
    } else if (MODE == 3){
      val += bias0[gn];
      val = fmaxf(val, 0.f);
      out0[gm*512 + gn] = f2bf(val);
    } else {
      val += bias0[gn] + bf2f(aux[gm*512 + gn]);
      outf[gm*512 + gn] = val;
    }
  }
}

// ---------- K3 v6: attention; K burst-staged to LDS, P overlays K,
// V-ring initial fills hoisted above softmax (hide cold-miss latency) ----------
// One block per (b,head), 4 waves x 48 rows. LDS 76.8 KB -> 2 blocks/CU.
__global__ __launch_bounds__(256, 2) void attn_kernel(
    const short* __restrict__ qg_, const short* __restrict__ kg_,
    const short* __restrict__ vtg_, const int* __restrict__ valid,
    short* __restrict__ outp){
  __shared__ short ldsb[38400];          // 76,800 B
  short* const Kl = ldsb;                // K: 2816 x 16B chunks (45,056 B)
  short* const Ps = ldsb;                // P overlays K after barrier

  int tid = threadIdx.x, lane = tid & 63, wid = tid >> 6;
  int lg = lane >> 4, l15 = lane & 15;
  int bh = blockIdx.x, b = bh >> 2, hh = bh & 3;
  const short* qg  = qg_  + (size_t)bh * (168*128);
  const short* kg  = kg_  + (size_t)bh * (168*128);
  const short* vtg = vtg_ + (size_t)bh * (128*168);

  // ---- burst-stage K: rows [176] x 128 cols; slot = chunk ^ ((row&1)<<2) ----
  #pragma unroll
  for (int r = 0; r < 11; r++){
    int c = r*256 + tid;
    int row = c >> 4;
    int g = (c & 15) ^ ((row & 1) << 2);
    GL16(kg + (size_t)row*128 + g*8, Kl + c*8);
  }

  int bits = 0;
  #pragma unroll
  for (int v = 0; v < 8; v++) bits |= (valid[b*8 + v] != 0) << v;
  if (bits == 0) bits = 255;
  float wk2[11];
  #pragma unroll
  for (int n = 0; n < 11; n++){
    int kt = n*16 + l15;
    int view = (kt * 781) >> 14;            // kt/21, exact for kt<176
    wk2[n] = ((bits >> view) & 1) ? 0.0f : -1.0e9f;
  }

  int row0 = wid * 48;
  f4v zf = {0.f,0.f,0.f,0.f};

  // ---- Q fragments from global (overlap with K staging) ----
  s8v qf[3][4];
  #pragma unroll
  for (int m=0;m<3;m++)
    #pragma unroll
    for (int kf=0;kf<4;kf++)
      qf[m][kf] = *(const s8v*)(qg + (size_t)(row0 + m*16 + l15)*128 + kf*32 + lg*8);

  asm volatile("s_waitcnt vmcnt(0)" ::: "memory");
  __builtin_amdgcn_s_barrier();

  // ---- S = Q @ K^T, K fragments from LDS ----
  f4v accS[3][11];
  #pragma unroll
  for (int m=0;m<3;m++)
    #pragma unroll
    for (int n=0;n<11;n++) accS[m][n] = zf;
  #pragma unroll
  for (int n=0;n<11;n++){
    s8v kb[4];
    #pragma unroll
    for (int kf=0;kf<4;kf++)
      kb[kf] = *(const s8v*)&Kl[(size_t)(n*16 + l15)*128 + (((kf*4 + lg) ^ ((l15 & 1) << 2)) << 3)];
    __builtin_amdgcn_s_setprio(1);
    #pragma unroll
    for (int kf=0;kf<4;kf++)
      #pragma unroll
      for (int m=0;m<3;m++)
        accS[m][n] = __builtin_amdgcn_mfma_f32_16x16x32_bf16(qf[m][kf], kb[kf], accS[m][n], 0,0,0);
    __builtin_amdgcn_s_setprio(0);
  }
  __builtin_amdgcn_s_barrier();   // all waves done reading K; P may overwrite

  // ---- V-ring fills 0,1 issued HERE: latency hides under softmax+P-write ----
  s8v vb[3][6];
  #pragma unroll
  for (int p=0;p<2;p++)
    #pragma unroll
    for (int kf=0;kf<6;kf++)
      vb[p][kf] = *(const s8v*)(vtg + (size_t)(p*16 + l15)*168 + kf*32 + lg*8);

  // ---- softmax (shift-free), write unnormalized P ----
  float inv_[3][4];
  #pragma unroll
  for (int m=0;m<3;m++){
    #pragma unroll
    for (int r=0;r<4;r++){
      int qtok = row0 + m*16 + lg*4 + r;
      float sum = 0.f;
      #pragma unroll
      for (int n=0;n<11;n++){
        float p = exp2f(fmaf(accS[m][n][r], SCALE2, wk2[n]));
        sum += p;
        Ps[qtok*200 + n*16 + l15] = f2bf(p);
      }
      sum += __shfl_xor(sum,1); sum += __shfl_xor(sum,2);
      sum += __shfl_xor(sum,4); sum += __shfl_xor(sum,8);
      inv_[m][r] = 1.0f / sum;
    }
  }
  {
    s8v z8 = {0,0,0,0,0,0,0,0};
    for (int i = lane; i < 96; i += 64){
      int rr = row0 + (i >> 1);
      *(s8v*)&Ps[rr*200 + 176 + (i&1)*8] = z8;
    }
  }

  // ---- O = P @ V with Vt 3-deep register prefetch ----
  s8v ap[3][6];
  #pragma unroll
  for (int m=0;m<3;m++)
    #pragma unroll
    for (int kf=0;kf<6;kf++)
      ap[m][kf] = *(const s8v*)&Ps[(row0 + m*16 + l15)*200 + kf*32 + lg*8];

  f4v accO[3][8];
  #pragma unroll
  for (int m=0;m<3;m++)
    #pragma unroll
    for (int n=0;n<8;n++) accO[m][n] = zf;
  #pragma unroll
  for (int n=0;n<8;n++){
    if (n < 6){
      #pragma unroll
      for (int kf=0;kf<6;kf++)
        vb[(n+2)%3][kf] = *(const s8v*)(vtg + (size_t)((n+2)*16 + l15)*168 + kf*32 + lg*8);
    }
    __builtin_amdgcn_s_setprio(1);
    #pragma unroll
    for (int kf=0;kf<6;kf++)
      #pragma unroll
      for (int m=0;m<3;m++)
        accO[m][n] = __builtin_amdgcn_mfma_f32_16x16x32_bf16(ap[m][kf], vb[n%3][kf], accO[m][n], 0,0,0);
    __builtin_amdgcn_s_setprio(0);
  }

  // ---- write attn_out [b*168+q][hh*128+d] bf16 (normalize) ----
  #pragma unroll
  for (int m=0;m<3;m++){
    #pragma unroll
    for (int r=0;r<4;r++){
      int qtok = row0 + m*16 + lg*4 + r;
      if (qtok < 168){
        float iv = inv_[m][r];
        size_t base = ((size_t)b*168 + qtok)*512 + hh*128;
        #pragma unroll
        for (int n=0;n<8;n++)
          outp[base + n*16 + l15] = f2bf(accO[m][n][r] * iv);
      }
    }
  }
}

// ---------- launch ----------
extern "C" void kernel_launch(void* const* d_in, const int* in_sizes, int n_in,
                              void* d_out, int out_size, void* d_ws, size_t ws_size,
                              hipStream_t stream) {
  const float* x     = (const float*)d_in[0];
  const int*   valid = (const int*)  d_in[1];
  const float* wq    = (const float*)d_in[2];
  const float* bq    = (const float*)d_in[3];
  const float* wk    = (const float*)d_in[4];
  const float* bk    = (const float*)d_in[5];
  const float* wv    = (const float*)d_in[6];
  const float* bv    = (const float*)d_in[7];
  const float* fcw   = (const float*)d_in[8];
  const float* fcb   = (const float*)d_in[9];
  const float* ln1g  = (const float*)d_in[10];
  const float* ln1b  = (const float*)d_in[11];
  const float* ln2g  = (const float*)d_in[12];
  const float* ln2b  = (const float*)d_in[13];
  const float* fc1w  = (const float*)d_in[14];
  const float* fc1b  = (const float*)d_in[15];
  const float* fc2w  = (const float*)d_in[16];
  const float* fc2b  = (const float*)d_in[17];

  char* ws = (char*)d_ws;
  short* h       = (short*)(ws + 0LL);            // later: attn_out, then g2
  short* q_ws    = (short*)(ws + 176160768LL);
  short* k_ws    = (short*)(ws + 352321536LL);    // later: a1
  short* vt_ws   = (short*)(ws + 528482304LL);    // later: x2b
  short* wb      = (short*)(ws + 704643072LL);    // bf16 weights [wq|wk|wv|fcw|fc1|fc2]
  short* attn_o  = h;
  short* g2      = h;
  short* a1      = k_ws;
  short* x2b     = vt_ws;
  float* outp    = (float*)d_out;

  convert_w<<<1536, 256, 0, stream>>>(wq, wk, wv, fcw, fc1w, fc2w, wb);
  ln1_kernel<<<MROWS/4, 256, 0, stream>>>(x, ln1g, ln1b, h);
  // QK projection (N=1024): 4 N-tiles x 672 M-tiles
  gemm_bt<0><<<dim3(4, MROWS/256), 512, 0, stream>>>(h, wb, bq, bk, nullptr, nullptr, q_ws, k_ws, nullptr);
  // V^T projection: wv @ h^T (M=512 -> 2 M-tiles; N=172032 -> 672 N-tiles)
  gemm_bt<1><<<dim3(2, MROWS/256), 512, 0, stream>>>(wb + 524288, h, bv, nullptr, nullptr, nullptr, vt_ws, nullptr, nullptr);
  attn_kernel<<<BATCH*NHEAD, 256, 0, stream>>>(q_ws, k_ws, vt_ws, valid, attn_o);
  // output projection + fused residual: x2b = bf16(x + proj + fc_b)
  gemm_bt<2><<<dim3(2, MROWS/256), 512, 0, stream>>>(attn_o, wb + 786432, fcb, nullptr, nullptr, x, x2b, nullptr, nullptr);
  ln2_kernel<<<MROWS/4, 256, 0, stream>>>(x2b, ln2g, ln2b, g2);
  // MLP
  gemm_bt<3><<<dim3(2, MROWS/256), 512, 0, stream>>>(g2, wb + 1048576, fc1b, nullptr, nullptr, nullptr, a1, nullptr, nullptr);
  gemm_bt<4><<<dim3(2, MROWS/256), 512, 0, stream>>>(a1, wb + 1310720, fc2b, nullptr, x2b, nullptr, nullptr, nullptr, outp);
}